// Round 13
// baseline (434.288 us; speedup 1.0000x reference)
//
#include <hip/hip_runtime.h>

// EMA Vector-Quantizer for MI355X (gfx950).
// N=16384 tokens, D=64, K=8192. Dominant cost: 16384x8192x64 fp32 GEMM for
// distance argmin (no fp32 MFMA on CDNA4 -> VALU; v_pk_fma_f32 floor 54.6us).
// Mechanism map (R2-R12): binding resource is VALU issue. Allocator pins 64
// arch VGPRs in every config except R8's (whose occupancy was too low);
// acc arrays > ~32 regs get shuttled through AGPRs (v_accvgpr_read/write),
// multiplying issue: scalar+shuttle ~323us, pk+shuttle ~256us (R12).
// R13: STOP fighting the allocator -- shrink the accumulator to fit 64 VGPRs.
// Thread tile 4n x 8k packed = 16 v2f = 32 acc regs; hot-loop demand ~50.
// 512-thr blocks (tx16 x ty32), block tile 128n x 128k, z_s 32KB ->
// 4 blocks/CU = 8 waves/SIMD (max occupancy). Only cold per-kb-tile state
// (bestd/wn) may shuttle -- once per 64 d-iters, negligible.

#define N_TOK 16384
#define K_EMB 8192
#define EMB_D 64
#define TN 128
#define GROUPS 8
#define KPG (K_EMB / GROUPS)   // 1024 codes per k-group, 8 kb-tiles of 128

typedef float v2f __attribute__((ext_vector_type(2)));

// d_out flat layout (float32), in reference return order:
// z_q (1048576) | loss | new_weight (524288) | new_cluster_size (8192) | new_embed_avg (524288)
#define OFF_LOSS 1048576
#define OFF_W    1048577
#define OFF_CS   1572865
#define OFF_EA   1581057

// scratch inside the z_q region of out (all < 1048576, overwritten by k_quant)
#define OUT_WT 0                        // w_t[d][k]: 64 x 8192 = 524288 floats
#define OUT_CD 524288                   // cand dist [GROUPS][N_TOK] = 131072
#define OUT_CI (524288 + 131072)        // cand idx  [GROUPS][N_TOK] = 131072

// ws float offsets
#define WS_NSUM  0
#define WS_LOSS  1
#define WS_WNORM 16
#define WS_IDX   (WS_WNORM + K_EMB)

// ---------------------------------------------------------------------------
// K0: wnorm[k]; transpose weight -> w_t[d][k] (in out); zero accumulators.
__global__ void k_prep(const float* __restrict__ weight,
                       float* __restrict__ out, float* __restrict__ ws) {
  int gid = blockIdx.x * 256 + threadIdx.x;     // 0..131071
  int row = gid >> 4;                            // codebook row 0..8191
  int l16 = gid & 15;
  float4 w4 = *(const float4*)(weight + row * EMB_D + l16 * 4);
  float s = w4.x * w4.x + w4.y * w4.y + w4.z * w4.z + w4.w * w4.w;
  #pragma unroll
  for (int off = 8; off > 0; off >>= 1) s += __shfl_xor(s, off, 16);
  if (l16 == 0) ws[WS_WNORM + row] = s;

  // transposed copy: w_t[d*8192 + row], d = l16*4+c
  out[OUT_WT + (l16 * 4 + 0) * K_EMB + row] = w4.x;
  out[OUT_WT + (l16 * 4 + 1) * K_EMB + row] = w4.y;
  out[OUT_WT + (l16 * 4 + 2) * K_EMB + row] = w4.z;
  out[OUT_WT + (l16 * 4 + 3) * K_EMB + row] = w4.w;

  #pragma unroll
  for (int j = 0; j < 4; ++j) out[OFF_EA + gid * 4 + j] = 0.f;
  if (gid < K_EMB) out[OFF_CS + gid] = 0.f;
  if (gid == 0) { out[OFF_LOSS] = 0.f; ws[WS_NSUM] = 0.f; ws[WS_LOSS] = 0.f; }
}

// ---------------------------------------------------------------------------
// K1: distance argmin. Block = 512 threads (tx 16 x ty 32); block tile
// 128n x 128k per kb-iter; thread tile 4n x 8k, acc as 2x8 v2f (16 v2f =
// 32 VGPRs -> fits the 64-VGPR allocation cleanly, no AGPR shuttles).
// grid (128, 8) = 1024 blocks = 4/CU; z_s 32KB; 64 VGPR -> 8 waves/SIMD.
// Inner loop: v_pk_fma_f32; z via one ds_read_b128 (4 distinct addrs/wave,
// broadcast); w via 2 contiguous global dwordx4 (L1-resident).
__global__ __launch_bounds__(512) void k_argmin(
    const float* __restrict__ z, const float* __restrict__ wt,
    const float* __restrict__ wnorm, float* __restrict__ cd,
    int* __restrict__ ci) {
  __shared__ __align__(16) float z_s[EMB_D * TN];  // [d][n], 32 KB
  const int t = threadIdx.x;
  const int n0 = blockIdx.x * TN;
  const int kbase = blockIdx.y * KPG;
  // z is (b, c, hw): z_flat[n][d] = z[b*65536 + d*1024 + hw], n = b*1024+hw.
  // TN=128 stays within one 1024-aligned b-slab (n0 is a multiple of 128).
  const float* zb = z + ((n0 >> 10) << 16) + (n0 & 1023);

  #pragma unroll
  for (int i = 0; i < 4; ++i) {
    int f4 = i * 512 + t;                 // 0..2047 float4s
    int d = f4 >> 5, c4 = (f4 & 31) * 4;
    *(float4*)(z_s + d * TN + c4) = *(const float4*)(zb + d * 1024 + c4);
  }
  __syncthreads();                        // the only barrier

  const int tx = t & 15, ty = t >> 4;     // tx -> k (16), ty -> n slab (32)
  const float* zrow = z_s + ty * 4;       // this thread's 4-row n-slab
  float bestd[4];
  int besti[4];
  #pragma unroll
  for (int i = 0; i < 4; ++i) { bestd[i] = 3.4e38f; besti[i] = 0; }

  for (int kb = 0; kb < KPG / 128; ++kb) {
    const int ktb = kbase + kb * 128;
    float4 wn0 = *(const float4*)(wnorm + ktb + tx * 4);
    float4 wn1 = *(const float4*)(wnorm + ktb + 64 + tx * 4);

    v2f acc2[2][8];                       // [n-pair][k]; .x=row 2p, .y=row 2p+1
    #pragma unroll
    for (int p = 0; p < 2; ++p)
      #pragma unroll
      for (int j = 0; j < 8; ++j) acc2[p][j] = (v2f)(0.f);

    const float* wp = wt + ktb + tx * 4;  // row stride K_EMB per d
    #pragma unroll 4
    for (int d = 0; d < EMB_D; ++d) {
      const v2f* z2p = (const v2f*)(zrow + d * TN);  // 2 n-row pairs (16B)
      v2f z2[2] = {z2p[0], z2p[1]};
      float4 w0 = *(const float4*)(wp);
      float4 w1 = *(const float4*)(wp + 64);
      wp += K_EMB;
      float wr[8] = {w0.x, w0.y, w0.z, w0.w, w1.x, w1.y, w1.z, w1.w};
      #pragma unroll
      for (int j = 0; j < 8; ++j) {
        v2f w2 = {wr[j], wr[j]};
        #pragma unroll
        for (int p = 0; p < 2; ++p)
          acc2[p][j] = __builtin_elementwise_fma(z2[p], w2, acc2[p][j]);
      }
    }

    // dist = |w|^2 - 2*dot. Per-thread k ascends over (g, j) -> strict <
    // keeps first-min; cross-thread ties resolved by index compare below.
    float wna[8] = {wn0.x, wn0.y, wn0.z, wn0.w, wn1.x, wn1.y, wn1.z, wn1.w};
    #pragma unroll
    for (int g = 0; g < 2; ++g)
      #pragma unroll
      for (int j = 0; j < 4; ++j) {
        int col = g * 4 + j;
        int kg = ktb + g * 64 + tx * 4 + j;
        float wn = wna[col];
        #pragma unroll
        for (int i = 0; i < 4; ++i) {
          float dot = (i & 1) ? acc2[i >> 1][col].y : acc2[i >> 1][col].x;
          float dist = fmaf(-2.f, dot, wn);
          if (dist < bestd[i]) { bestd[i] = dist; besti[i] = kg; }
        }
      }
  }

  // Reduce across the 16 tx threads sharing each n (lanes of one wave,
  // width 16; tx == lane & 15 since ty is constant per 16-lane span).
  #pragma unroll
  for (int i = 0; i < 4; ++i) {
    float bd = bestd[i]; int bi = besti[i];
    #pragma unroll
    for (int off = 8; off > 0; off >>= 1) {
      float od = __shfl_xor(bd, off, 16);
      int oi = __shfl_xor(bi, off, 16);
      if (od < bd || (od == bd && oi < bi)) { bd = od; bi = oi; }
    }
    if (tx == 0) {
      int n = n0 + ty * 4 + i;
      cd[blockIdx.y * N_TOK + n] = bd;
      ci[blockIdx.y * N_TOK + n] = bi;
    }
  }
}

// ---------------------------------------------------------------------------
// K2: reduce the GROUPS candidates per token; enc_sum atomics.
// Groups cover ascending k-ranges, so strict < keeps smallest index on tie.
__global__ void k_reduce(const float* __restrict__ cd, const int* __restrict__ ci,
                         int* __restrict__ idx, float* __restrict__ enc) {
  int n = blockIdx.x * 256 + threadIdx.x;
  float bd = cd[n]; int bi = ci[n];
  #pragma unroll
  for (int g = 1; g < GROUPS; ++g) {
    float od = cd[g * N_TOK + n];
    int oi = ci[g * N_TOK + n];
    if (od < bd) { bd = od; bi = oi; }
  }
  idx[n] = bi;
  atomicAdd(enc + bi, 1.0f);
}

// ---------------------------------------------------------------------------
// K3: z_q gather + straight-through output + loss partials + embed_sum atomics.
__global__ void k_quant(const float* __restrict__ z, const float* __restrict__ weight,
                        const int* __restrict__ idx, float* __restrict__ out,
                        float* __restrict__ embed_acc, float* __restrict__ ws) {
  int base = blockIdx.x * 1024 + threadIdx.x;
  float lsum = 0.f;
  #pragma unroll
  for (int i = 0; i < 4; ++i) {
    int e = base + i * 256;               // (b,c,hw) flat, same layout as z
    int c = (e >> 10) & 63;
    int n = ((e >> 16) << 10) | (e & 1023);
    int k = idx[n];
    float zv = z[e];
    float q = weight[k * EMB_D + c];
    out[e] = zv + (q - zv);               // straight-through value
    float d = q - zv;
    lsum += d * d;
    atomicAdd(embed_acc + k * EMB_D + c, zv);
  }
  #pragma unroll
  for (int off = 32; off > 0; off >>= 1) lsum += __shfl_xor(lsum, off, 64);
  __shared__ float red[4];
  int lane = threadIdx.x & 63, wv = threadIdx.x >> 6;
  if (lane == 0) red[wv] = lsum;
  __syncthreads();
  if (threadIdx.x == 0)
    atomicAdd(ws + WS_LOSS, red[0] + red[1] + red[2] + red[3]);
}

// ---------------------------------------------------------------------------
// K4: new_cluster_size (in place over enc_sum), n-sum, loss finalize.
__global__ void k_cluster(const float* __restrict__ cluster_in,
                          float* __restrict__ out, float* __restrict__ ws) {
  int k = blockIdx.x * 256 + threadIdx.x;
  float ncs = cluster_in[k] * 0.99f + 0.01f * out[OFF_CS + k];
  out[OFF_CS + k] = ncs;
  float s = ncs;
  #pragma unroll
  for (int off = 32; off > 0; off >>= 1) s += __shfl_xor(s, off, 64);
  __shared__ float red[4];
  int lane = threadIdx.x & 63, wv = threadIdx.x >> 6;
  if (lane == 0) red[wv] = s;
  __syncthreads();
  if (threadIdx.x == 0) atomicAdd(ws + WS_NSUM, red[0] + red[1] + red[2] + red[3]);
  if (blockIdx.x == 0 && threadIdx.x == 0)
    out[OFF_LOSS] = 0.25f * ws[WS_LOSS] * (1.0f / 1048576.0f);
}

// ---------------------------------------------------------------------------
// K5: smoothed cluster sizes -> new_weight; new_embed_avg (in place).
__global__ void k_final(const float* __restrict__ embed_avg,
                        float* __restrict__ out, const float* __restrict__ ws) {
  int e = blockIdx.x * 256 + threadIdx.x;   // < 524288
  int k = e >> 6;
  float ncs = out[OFF_CS + k];
  float nsum = ws[WS_NSUM];
  float sm = (ncs + 1e-5f) / (nsum + K_EMB * 1e-5f) * nsum;
  float ea = embed_avg[e] * 0.99f + 0.01f * out[OFF_EA + e];
  out[OFF_EA + e] = ea;
  out[OFF_W + e] = ea / sm;
}

// ---------------------------------------------------------------------------
extern "C" void kernel_launch(void* const* d_in, const int* in_sizes, int n_in,
                              void* d_out, int out_size, void* d_ws, size_t ws_size,
                              hipStream_t stream) {
  const float* z = (const float*)d_in[0];
  const float* weight = (const float*)d_in[1];
  const float* cluster = (const float*)d_in[2];
  const float* embed_avg = (const float*)d_in[3];
  float* out = (float*)d_out;
  float* ws = (float*)d_ws;
  float* wnorm = ws + WS_WNORM;
  int* idx = (int*)(ws + WS_IDX);
  float* wt = out + OUT_WT;               // scratch in z_q region
  float* cd = out + OUT_CD;
  int* ci = (int*)(out + OUT_CI);

  hipLaunchKernelGGL(k_prep, dim3(512), dim3(256), 0, stream, weight, out, ws);
  hipLaunchKernelGGL(k_argmin, dim3(N_TOK / TN, GROUPS), dim3(512), 0, stream,
                     z, wt, wnorm, cd, ci);
  hipLaunchKernelGGL(k_reduce, dim3(N_TOK / 256), dim3(256), 0, stream,
                     cd, ci, idx, out + OFF_CS);
  hipLaunchKernelGGL(k_quant, dim3(1024), dim3(256), 0, stream,
                     z, weight, idx, out, out + OFF_EA, ws);
  hipLaunchKernelGGL(k_cluster, dim3(K_EMB / 256), dim3(256), 0, stream,
                     cluster, out, ws);
  hipLaunchKernelGGL(k_final, dim3(524288 / 256), dim3(256), 0, stream,
                     embed_avg, out, ws);
}

// Round 15
// 372.843 us; speedup vs baseline: 1.1648x; 1.1648x over previous
//
#include <hip/hip_runtime.h>

// EMA Vector-Quantizer for MI355X (gfx950).
// N=16384 tokens, D=64, K=8192. Dominant cost: 16384x8192x64 fp32 GEMM for
// distance argmin (no fp32 MFMA on CDNA4 -> VALU; v_pk_fma_f32 floor 54.6us).
// R13 post-mortem: binding resource is VECTOR-MEMORY OPERAND RETURN, not VALU
// issue (clean 56-VGPR pk codegen landed 293us ~= w-traffic 8.6GB / L1-return
// 64B/cyc/CU = 218us + z/LDS). R14/R15: take w OFF the vector path entirely --
// wave-uniform k so w comes via s_load into SGPRs (scalar cache, separate
// pipe); pk_fma reads the SGPR pair as its one scalar operand. z stays in LDS
// (0.5 B/MAC -> LDS-bound floor ~82us).
// R14 crashed: staging loop iterated i<32 instead of i<8 (4096 float4s /
// 512 threads), writing 4x past z_s and reading past z. R15 fixes that bound;
// all else identical.
// Layout: 512-thr blocks = 8 waves SHARING one 256-token z_s (64KB);
// waves split k (128 codes each). Lane = 4 tokens; chunk = 8 codes ->
// acc2[4][4] = 32 VGPRs (fits the 64-VGPR allocation, no AGPR shuttles).
// Per-(n,k) dot remains a sequential-d fma chain (pk pairs are k-pairs,
// not d-splits) -> arithmetic identical to all passing rounds.

#define N_TOK 16384
#define K_EMB 8192
#define EMB_D 64
#define TN 256
#define GROUPS 8
#define KPG (K_EMB / GROUPS)   // 1024 codes per k-group; 128 per wave

typedef float v2f __attribute__((ext_vector_type(2)));

// d_out flat layout (float32), in reference return order:
// z_q (1048576) | loss | new_weight (524288) | new_cluster_size (8192) | new_embed_avg (524288)
#define OFF_LOSS 1048576
#define OFF_W    1048577
#define OFF_CS   1572865
#define OFF_EA   1581057

// scratch inside the z_q region of out (all < 1048576, overwritten by k_quant)
#define OUT_WT 0                        // w_t[d][k]: 64 x 8192 = 524288 floats
#define OUT_CD 524288                   // cand dist [GROUPS][N_TOK] = 131072
#define OUT_CI (524288 + 131072)        // cand idx  [GROUPS][N_TOK] = 131072

// ws float offsets
#define WS_NSUM  0
#define WS_LOSS  1
#define WS_WNORM 16
#define WS_IDX   (WS_WNORM + K_EMB)

// ---------------------------------------------------------------------------
// K0: wnorm[k]; transpose weight -> w_t[d][k] (in out); zero accumulators.
__global__ void k_prep(const float* __restrict__ weight,
                       float* __restrict__ out, float* __restrict__ ws) {
  int gid = blockIdx.x * 256 + threadIdx.x;     // 0..131071
  int row = gid >> 4;                            // codebook row 0..8191
  int l16 = gid & 15;
  float4 w4 = *(const float4*)(weight + row * EMB_D + l16 * 4);
  float s = w4.x * w4.x + w4.y * w4.y + w4.z * w4.z + w4.w * w4.w;
  #pragma unroll
  for (int off = 8; off > 0; off >>= 1) s += __shfl_xor(s, off, 16);
  if (l16 == 0) ws[WS_WNORM + row] = s;

  // transposed copy: w_t[d*8192 + row], d = l16*4+c
  out[OUT_WT + (l16 * 4 + 0) * K_EMB + row] = w4.x;
  out[OUT_WT + (l16 * 4 + 1) * K_EMB + row] = w4.y;
  out[OUT_WT + (l16 * 4 + 2) * K_EMB + row] = w4.z;
  out[OUT_WT + (l16 * 4 + 3) * K_EMB + row] = w4.w;

  #pragma unroll
  for (int j = 0; j < 4; ++j) out[OFF_EA + gid * 4 + j] = 0.f;
  if (gid < K_EMB) out[OFF_CS + gid] = 0.f;
  if (gid == 0) { out[OFF_LOSS] = 0.f; ws[WS_NSUM] = 0.f; ws[WS_LOSS] = 0.f; }
}

// ---------------------------------------------------------------------------
// K1: distance argmin. Block = 512 threads = 8 waves sharing 256 tokens;
// wave w scans k-range [kbase + w*128, +128); lane owns 4 tokens.
// grid (64, 8) = 512 blocks = 2/CU = 4 waves/SIMD; z_s 64KB.
// Per d-iter: 1 ds_read_b128 (z, stride-1 conflict-free) + wave-uniform
// s_load (w row pairs in SGPRs) + 16 v_pk_fma_f32 (acc2[4][4] = 32 VGPRs).
__global__ __launch_bounds__(512) void k_argmin(
    const float* __restrict__ z, const float* __restrict__ wt,
    const float* __restrict__ wnorm, float* __restrict__ cd,
    int* __restrict__ ci) {
  __shared__ __align__(16) float z_s[EMB_D * TN];  // [d][n], 64 KB
  const int t = threadIdx.x;
  const int n0 = blockIdx.x * TN;
  const int kbase = blockIdx.y * KPG;
  // z is (b, c, hw): z_flat[n][d] = z[b*65536 + d*1024 + hw], n = b*1024+hw.
  // TN=256 stays within one 1024-aligned b-slab (n0 is a multiple of 256).
  const float* zb = z + ((n0 >> 10) << 16) + (n0 & 1023);

  // 16384 floats = 4096 float4s; 512 threads -> 8 iterations (R14 had 32:
  // 4x out-of-bounds on both LDS and global -> the crash).
  #pragma unroll
  for (int i = 0; i < 8; ++i) {
    int f4 = i * 512 + t;                 // 0..4095 float4s
    int d = f4 >> 6, c4 = (f4 & 63) * 4;
    *(float4*)(z_s + d * TN + c4) = *(const float4*)(zb + d * 1024 + c4);
  }
  __syncthreads();

  const int lane = t & 63;
  // wave id: provably wave-uniform -> w addresses become SGPR (s_load).
  const int wid = __builtin_amdgcn_readfirstlane(t >> 6);
  const int k0base = kbase + wid * 128;
  const float* zlane = z_s + lane * 4;    // this lane's 4 tokens

  float bestd[4];
  int besti[4];
  #pragma unroll
  for (int i = 0; i < 4; ++i) { bestd[i] = 3.4e38f; besti[i] = 0; }

  for (int kc = 0; kc < 16; ++kc) {       // 16 chunks of 8 codes
    const int k0 = k0base + kc * 8;
    const float* wrow = wt + k0;          // + d*K_EMB per d; uniform address

    v2f acc2[4][4];                       // [n][k-pair]; .x=k even, .y=k odd
    #pragma unroll
    for (int n = 0; n < 4; ++n)
      #pragma unroll
      for (int p = 0; p < 4; ++p) acc2[n][p] = (v2f)(0.f);

    #pragma unroll 4
    for (int d = 0; d < EMB_D; ++d) {
      float4 zf = *(const float4*)(zlane + d * TN);   // ds_read_b128
      const v2f* wv = (const v2f*)(wrow + (size_t)d * K_EMB);  // s_load x4
      v2f w0 = wv[0], w1 = wv[1], w2 = wv[2], w3 = wv[3];
      float zr[4] = {zf.x, zf.y, zf.z, zf.w};
      #pragma unroll
      for (int n = 0; n < 4; ++n) {
        v2f zn = {zr[n], zr[n]};          // op_sel broadcast (free)
        acc2[n][0] = __builtin_elementwise_fma(zn, w0, acc2[n][0]);
        acc2[n][1] = __builtin_elementwise_fma(zn, w1, acc2[n][1]);
        acc2[n][2] = __builtin_elementwise_fma(zn, w2, acc2[n][2]);
        acc2[n][3] = __builtin_elementwise_fma(zn, w3, acc2[n][3]);
      }
    }

    // dist = |w|^2 - 2*dot; k ascends (kc, kk) + strict <  == first-min.
    #pragma unroll
    for (int kk = 0; kk < 8; ++kk) {
      float wn = wnorm[k0 + kk];          // uniform -> scalar load
      #pragma unroll
      for (int n = 0; n < 4; ++n) {
        float dot = (kk & 1) ? acc2[n][kk >> 1].y : acc2[n][kk >> 1].x;
        float dist = fmaf(-2.f, dot, wn);
        if (dist < bestd[n]) { bestd[n] = dist; besti[n] = k0 + kk; }
      }
    }
  }

  // Block combine: stash per-wave bests in z_s (done reading it), then the
  // first 256 threads reduce 8 waves in ascending-k order (strict < keeps
  // the earlier wave, i.e. the smaller k, on ties).
  __syncthreads();
  #pragma unroll
  for (int i = 0; i < 4; ++i) {
    int n = lane * 4 + i;
    z_s[wid * 256 + n] = bestd[i];
    ((int*)z_s)[2048 + wid * 256 + n] = besti[i];
  }
  __syncthreads();
  if (t < 256) {
    int n = t;
    float bd = z_s[n];
    int bi = ((int*)z_s)[2048 + n];
    #pragma unroll
    for (int w = 1; w < 8; ++w) {
      float od = z_s[w * 256 + n];
      int oi = ((int*)z_s)[2048 + w * 256 + n];
      if (od < bd) { bd = od; bi = oi; }
    }
    cd[blockIdx.y * N_TOK + n0 + n] = bd;
    ci[blockIdx.y * N_TOK + n0 + n] = bi;
  }
}

// ---------------------------------------------------------------------------
// K2: reduce the GROUPS candidates per token; enc_sum atomics.
// Groups cover ascending k-ranges, so strict < keeps smallest index on tie.
__global__ void k_reduce(const float* __restrict__ cd, const int* __restrict__ ci,
                         int* __restrict__ idx, float* __restrict__ enc) {
  int n = blockIdx.x * 256 + threadIdx.x;
  float bd = cd[n]; int bi = ci[n];
  #pragma unroll
  for (int g = 1; g < GROUPS; ++g) {
    float od = cd[g * N_TOK + n];
    int oi = ci[g * N_TOK + n];
    if (od < bd) { bd = od; bi = oi; }
  }
  idx[n] = bi;
  atomicAdd(enc + bi, 1.0f);
}

// ---------------------------------------------------------------------------
// K3: z_q gather + straight-through output + loss partials + embed_sum atomics.
__global__ void k_quant(const float* __restrict__ z, const float* __restrict__ weight,
                        const int* __restrict__ idx, float* __restrict__ out,
                        float* __restrict__ embed_acc, float* __restrict__ ws) {
  int base = blockIdx.x * 1024 + threadIdx.x;
  float lsum = 0.f;
  #pragma unroll
  for (int i = 0; i < 4; ++i) {
    int e = base + i * 256;               // (b,c,hw) flat, same layout as z
    int c = (e >> 10) & 63;
    int n = ((e >> 16) << 10) | (e & 1023);
    int k = idx[n];
    float zv = z[e];
    float q = weight[k * EMB_D + c];
    out[e] = zv + (q - zv);               // straight-through value
    float d = q - zv;
    lsum += d * d;
    atomicAdd(embed_acc + k * EMB_D + c, zv);
  }
  #pragma unroll
  for (int off = 32; off > 0; off >>= 1) lsum += __shfl_xor(lsum, off, 64);
  __shared__ float red[4];
  int lane = threadIdx.x & 63, wv = threadIdx.x >> 6;
  if (lane == 0) red[wv] = lsum;
  __syncthreads();
  if (threadIdx.x == 0)
    atomicAdd(ws + WS_LOSS, red[0] + red[1] + red[2] + red[3]);
}

// ---------------------------------------------------------------------------
// K4: new_cluster_size (in place over enc_sum), n-sum, loss finalize.
__global__ void k_cluster(const float* __restrict__ cluster_in,
                          float* __restrict__ out, float* __restrict__ ws) {
  int k = blockIdx.x * 256 + threadIdx.x;
  float ncs = cluster_in[k] * 0.99f + 0.01f * out[OFF_CS + k];
  out[OFF_CS + k] = ncs;
  float s = ncs;
  #pragma unroll
  for (int off = 32; off > 0; off >>= 1) s += __shfl_xor(s, off, 64);
  __shared__ float red[4];
  int lane = threadIdx.x & 63, wv = threadIdx.x >> 6;
  if (lane == 0) red[wv] = s;
  __syncthreads();
  if (threadIdx.x == 0) atomicAdd(ws + WS_NSUM, red[0] + red[1] + red[2] + red[3]);
  if (blockIdx.x == 0 && threadIdx.x == 0)
    out[OFF_LOSS] = 0.25f * ws[WS_LOSS] * (1.0f / 1048576.0f);
}

// ---------------------------------------------------------------------------
// K5: smoothed cluster sizes -> new_weight; new_embed_avg (in place).
__global__ void k_final(const float* __restrict__ embed_avg,
                        float* __restrict__ out, const float* __restrict__ ws) {
  int e = blockIdx.x * 256 + threadIdx.x;   // < 524288
  int k = e >> 6;
  float ncs = out[OFF_CS + k];
  float nsum = ws[WS_NSUM];
  float sm = (ncs + 1e-5f) / (nsum + K_EMB * 1e-5f) * nsum;
  float ea = embed_avg[e] * 0.99f + 0.01f * out[OFF_EA + e];
  out[OFF_EA + e] = ea;
  out[OFF_W + e] = ea / sm;
}

// ---------------------------------------------------------------------------
extern "C" void kernel_launch(void* const* d_in, const int* in_sizes, int n_in,
                              void* d_out, int out_size, void* d_ws, size_t ws_size,
                              hipStream_t stream) {
  const float* z = (const float*)d_in[0];
  const float* weight = (const float*)d_in[1];
  const float* cluster = (const float*)d_in[2];
  const float* embed_avg = (const float*)d_in[3];
  float* out = (float*)d_out;
  float* ws = (float*)d_ws;
  float* wnorm = ws + WS_WNORM;
  int* idx = (int*)(ws + WS_IDX);
  float* wt = out + OUT_WT;               // scratch in z_q region
  float* cd = out + OUT_CD;
  int* ci = (int*)(out + OUT_CI);

  hipLaunchKernelGGL(k_prep, dim3(512), dim3(256), 0, stream, weight, out, ws);
  hipLaunchKernelGGL(k_argmin, dim3(N_TOK / TN, GROUPS), dim3(512), 0, stream,
                     z, wt, wnorm, cd, ci);
  hipLaunchKernelGGL(k_reduce, dim3(N_TOK / 256), dim3(256), 0, stream,
                     cd, ci, idx, out + OFF_CS);
  hipLaunchKernelGGL(k_quant, dim3(1024), dim3(256), 0, stream,
                     z, weight, idx, out, out + OFF_EA, ws);
  hipLaunchKernelGGL(k_cluster, dim3(K_EMB / 256), dim3(256), 0, stream,
                     cluster, out, ws);
  hipLaunchKernelGGL(k_final, dim3(524288 / 256), dim3(256), 0, stream,
                     embed_avg, out, ws);
}